// Round 8
// baseline (331.447 us; speedup 1.0000x reference)
//
#include <hip/hip_runtime.h>

#define B_ 8192
#define IN_ 1024
#define OUT_ 256
#define E_ 16
#define KTOP 3
#define H_ 512
#define MAXSLOTS 26624   // 24576 + 16*127 rounded up
#define NTILES 208       // MAXSLOTS / 128
#define HBLK 16          // dispatch blocks
#define GBLK 2048        // gating blocks in k_stage1

typedef __bf16 bf16;
typedef __bf16 bf16x4 __attribute__((ext_vector_type(4)));
typedef __bf16 bf16x8 __attribute__((ext_vector_type(8)));
typedef float f32x4 __attribute__((ext_vector_type(4)));

// ================= stage1: gating + W transposes + inits, ONE launch =================
// blocks [0,2048): gating (4 rows each, wg staged to LDS per 256-row quarter)
// [2048,4096): W1 transpose; [4096,4608): W2 transpose; [4608,4712): row_ids=-1;
// 4712: tile_expert=-1.
__global__ __launch_bounds__(256) void k_stage1(
    const float* __restrict__ x, const float* __restrict__ wg,
    const float* __restrict__ W1, const float* __restrict__ W2,
    bf16* __restrict__ xbf, int* __restrict__ top_idx, float* __restrict__ top_gate,
    bf16* __restrict__ w1t, bf16* __restrict__ w2t,
    int* __restrict__ row_ids, int* __restrict__ tile_expert) {
    __shared__ __align__(16) float smem[5120];  // 20 KB: gating wg-stage (padded) / transpose tile
    int bx = blockIdx.x;
    int t = threadIdx.x;
    if (bx < GBLK) {
        // ---- gating: 4 rows/block; wg quarter [256j][16e] staged as padded rows of 5 float4 ----
        int lane = t & 63;
        int row = bx * 4 + (t >> 6);
        float acc[16];
#pragma unroll
        for (int e = 0; e < 16; e++) acc[e] = 0.f;
        const float4* x4p = (const float4*)(x + (size_t)row * IN_);
        float4* swg4 = (float4*)smem;
        for (int q = 0; q < 4; q++) {
            const float4* src = (const float4*)(wg + q * 4096);
#pragma unroll
            for (int i = 0; i < 4; i++) {
                int f = i * 256 + t;        // float4 idx within quarter [0,1024)
                swg4[(f >> 2) * 5 + (f & 3)] = src[f];
            }
            __syncthreads();
            float4 xv = x4p[q * 64 + lane];
            bf16x4 xb;
            xb[0] = (bf16)xv.x; xb[1] = (bf16)xv.y; xb[2] = (bf16)xv.z; xb[3] = (bf16)xv.w;
            *(bf16x4*)(xbf + (size_t)row * IN_ + (q * 64 + lane) * 4) = xb;
            float xs[4] = {xv.x, xv.y, xv.z, xv.w};
#pragma unroll
            for (int i = 0; i < 4; i++) {
                int r = lane * 4 + i;       // j-row within quarter
#pragma unroll
                for (int e4 = 0; e4 < 4; e4++) {
                    float4 wv = swg4[r * 5 + e4];
                    acc[e4 * 4 + 0] += xs[i] * wv.x;
                    acc[e4 * 4 + 1] += xs[i] * wv.y;
                    acc[e4 * 4 + 2] += xs[i] * wv.z;
                    acc[e4 * 4 + 3] += xs[i] * wv.w;
                }
            }
            __syncthreads();
        }
#pragma unroll
        for (int e = 0; e < 16; e++) {
#pragma unroll
            for (int s = 32; s > 0; s >>= 1) acc[e] += __shfl_xor(acc[e], s, 64);
        }
        if (lane == 0) {
            float v[16];
#pragma unroll
            for (int e = 0; e < 16; e++) v[e] = acc[e];
            int idx[KTOP];
            float val[KTOP];
#pragma unroll
            for (int k = 0; k < KTOP; k++) {
                int best = 0;
                float bv = v[0];
                for (int e = 1; e < 16; e++) {
                    if (v[e] > bv) { bv = v[e]; best = e; }
                }
                idx[k] = best; val[k] = bv; v[best] = -1e30f;
            }
            float e1 = __expf(val[1] - val[0]);
            float e2 = __expf(val[2] - val[0]);
            float inv = 1.f / (1.f + e1 + e2);
            float g[KTOP] = {inv, e1 * inv, e2 * inv};
#pragma unroll
            for (int k = 0; k < KTOP; k++) {
                top_idx[row * KTOP + k] = idx[k];
                top_gate[row * KTOP + k] = g[k];
            }
        }
        return;
    }
    if (bx >= 4608) {
        if (bx < 4712) {            // row_ids = -1 (104*256 == MAXSLOTS)
            row_ids[(bx - 4608) * 256 + t] = -1;
        } else {                    // tile_expert
            if (t < NTILES) tile_expert[t] = -1;
        }
        return;
    }
    // ---- W transpose+convert: in [E][K][N] f32 -> out [E][N][K] bf16 ----
    float (*tile)[65] = (float(*)[65])smem;   // 64*65*4 = 16.6 KB < 20 KB
    const float* in; bf16* out; int Kd, Nd, e, tk, tn;
    if (bx < 4096) {            // W1: 16 experts x (16 x 8) tiles
        int b1x = bx - 2048;
        in = W1; out = w1t; Kd = IN_; Nd = H_;
        e = b1x >> 7; int tt = b1x & 127; tk = tt >> 3; tn = tt & 7;
    } else {                    // W2: 16 experts x (8 x 4) tiles
        int b2x = bx - 4096;
        in = W2; out = w2t; Kd = H_; Nd = OUT_;
        e = b2x >> 5; int tt = b2x & 31; tk = tt >> 2; tn = tt & 3;
    }
    int r = t >> 6, c = t & 63;
    const float* src = in + ((size_t)e * Kd + tk * 64) * Nd + (size_t)tn * 64;
#pragma unroll
    for (int i = 0; i < 16; i++) {
        int rr = r + i * 4;
        tile[rr][c] = src[(size_t)rr * Nd + c];
    }
    __syncthreads();
    bf16* dst = out + ((size_t)e * Nd + tn * 64) * Kd + (size_t)tk * 64;
#pragma unroll
    for (int i = 0; i < 16; i++) {
        int rr = r + i * 4;
        dst[(size_t)rr * Kd + c] = (bf16)tile[c][rr];
    }
}

// ---------------- dispatch: hist + scan + scatter fused (16 blocks, zero global atomics) ----------------
__global__ __launch_bounds__(256) void k_dispatch(
    const int* __restrict__ top_idx, const float* __restrict__ top_gate,
    int* __restrict__ counts, int* __restrict__ tile_expert,
    int* __restrict__ row_ids, int* __restrict__ rowslot,
    float* __restrict__ partial_imp) {
    __shared__ int wtot[4][16];
    __shared__ int wpre[4][16];
    __shared__ int sbase[16];
    __shared__ int lcnt[16];
    __shared__ float limp[16];
    int t = threadIdx.x;
    int w = t >> 6;
    int blk = blockIdx.x;
    int tot[16], pre[16];
#pragma unroll
    for (int k = 0; k < 16; k++) { tot[k] = 0; pre[k] = 0; }
    for (int c = 0; c < HBLK; c++) {
#pragma unroll
        for (int j = 0; j < 6; j++) {
            int e = top_idx[c * 1536 + j * 256 + t];
#pragma unroll
            for (int k = 0; k < 16; k++) {
                int n = (int)__popcll(__ballot(e == k));
                tot[k] += n;
                if (c < blk) pre[k] += n;
            }
        }
    }
    int lane = t & 63;
    if (lane == 0) {
#pragma unroll
        for (int k = 0; k < 16; k++) { wtot[w][k] = tot[k]; wpre[w][k] = pre[k]; }
    }
    if (t < 16) { lcnt[t] = 0; limp[t] = 0.f; }
    __syncthreads();
    if (t < 16) {
        int off = 0;
        for (int e = 0; e < 16; e++) {
            int ce = wtot[0][e] + wtot[1][e] + wtot[2][e] + wtot[3][e];
            if (e == t) break;
            off += (ce + 127) & ~127;
        }
        int cnt_t = wtot[0][t] + wtot[1][t] + wtot[2][t] + wtot[3][t];
        int pre_t = wpre[0][t] + wpre[1][t] + wpre[2][t] + wpre[3][t];
        sbase[t] = off + pre_t;
        if (blk == 0) {
            counts[t] = cnt_t;
            int pd = (cnt_t + 127) & ~127;
            for (int tt = off >> 7; tt < (off + pd) >> 7; ++tt) tile_expert[tt] = t;
        }
    }
    __syncthreads();
#pragma unroll
    for (int j = 0; j < 6; j++) {
        int gid = blk * 1536 + j * 256 + t;
        int e = top_idx[gid];
        float g = top_gate[gid];
        int rank = atomicAdd(&lcnt[e], 1);
        atomicAdd(&limp[e], g);
        int slot = sbase[e] + rank;
        row_ids[slot] = gid / KTOP;
        rowslot[gid] = slot;
    }
    __syncthreads();
    if (t < 16) partial_imp[blk * 16 + t] = limp[t];
}

// ======================= GEMMs: barrier-free, direct global->VGPR fragments =======================
// Each lane's MFMA fragment is one contiguous 16B chunk; 2-deep register ping-pong
// prefetch; NO LDS, NO __syncthreads in the K-loop -> no vmcnt(0) barrier drain.
// Wave-level 2x load amplification is served by L2 (32 KB/iter/block, blocks share via L3).
// Grid: x = n (fastest) so co-dispatched siblings share A rows (R5-measured win).

// ---------------- GEMM1: h = relu(gather(x) @ W1[e] + b1[e]) -> bf16 ----------------
__global__ __launch_bounds__(256) void k_gemm1(
    const bf16* __restrict__ xbf, const bf16* __restrict__ w1t,
    const float* __restrict__ b1, const int* __restrict__ row_ids,
    const int* __restrict__ tile_expert, bf16* __restrict__ h) {
    int e = tile_expert[blockIdx.y];
    if (e < 0) return;
    int slot_base = blockIdx.y * 128;
    int nbase = blockIdx.x * 128;
    int t = threadIdx.x, w = t >> 6, lane = t & 63;
    int wm = (w >> 1) * 64, wn = (w & 1) * 64;
    int lm = lane & 15, lq = lane >> 4;
    const bf16* ap[4];
    const bf16* bp[4];
#pragma unroll
    for (int i = 0; i < 4; i++) {
        int rid = row_ids[slot_base + wm + i * 16 + lm];
        rid = rid < 0 ? 0 : rid;                      // dead slots: any row; output never combined
        ap[i] = xbf + (size_t)rid * IN_ + lq * 8;
        bp[i] = w1t + ((size_t)e * H_ + nbase + wn + i * 16 + lm) * IN_ + lq * 8;
    }
    f32x4 acc[4][4] = {};
    bf16x8 abuf[2][4], bbuf[2][4];
#pragma unroll
    for (int i = 0; i < 4; i++) {
        abuf[0][i] = *(const bf16x8*)(ap[i]);
        bbuf[0][i] = *(const bf16x8*)(bp[i]);
        abuf[1][i] = *(const bf16x8*)(ap[i] + 32);
        bbuf[1][i] = *(const bf16x8*)(bp[i] + 32);
    }
#pragma unroll 4
    for (int k0 = 0; k0 < IN_; k0 += 32) {
        int p = (k0 >> 5) & 1;
#pragma unroll
        for (int mi = 0; mi < 4; mi++)
#pragma unroll
            for (int ni = 0; ni < 4; ni++)
                acc[mi][ni] = __builtin_amdgcn_mfma_f32_16x16x32_bf16(abuf[p][mi], bbuf[p][ni], acc[mi][ni], 0, 0, 0);
        if (k0 + 64 < IN_) {
#pragma unroll
            for (int i = 0; i < 4; i++) {
                abuf[p][i] = *(const bf16x8*)(ap[i] + k0 + 64);
                bbuf[p][i] = *(const bf16x8*)(bp[i] + k0 + 64);
            }
        }
    }
#pragma unroll
    for (int mi = 0; mi < 4; mi++) {
#pragma unroll
        for (int ni = 0; ni < 4; ni++) {
            int colg = nbase + wn + ni * 16 + lm;
            float bias = b1[e * H_ + colg];
#pragma unroll
            for (int r = 0; r < 4; r++) {
                int rowl = wm + mi * 16 + lq * 4 + r;
                float v = acc[mi][ni][r] + bias;
                v = v > 0.f ? v : 0.f;
                h[(size_t)(slot_base + rowl) * H_ + colg] = (bf16)v;
            }
        }
    }
}

// ---------------- GEMM2: eout[slot] = h[slot] @ W2[e] + b2[e]  (f32, barrier-free) ----------------
__global__ __launch_bounds__(256) void k_gemm2(
    const bf16* __restrict__ h, const bf16* __restrict__ w2t,
    const float* __restrict__ b2, const int* __restrict__ tile_expert,
    float* __restrict__ eout) {
    int e = tile_expert[blockIdx.y];
    if (e < 0) return;
    int slot_base = blockIdx.y * 128;
    int nbase = blockIdx.x * 128;
    int t = threadIdx.x, w = t >> 6, lane = t & 63;
    int wm = (w >> 1) * 64, wn = (w & 1) * 64;
    int lm = lane & 15, lq = lane >> 4;
    const bf16* ap[4];
    const bf16* bp[4];
#pragma unroll
    for (int i = 0; i < 4; i++) {
        ap[i] = h + (size_t)(slot_base + wm + i * 16 + lm) * H_ + lq * 8;
        bp[i] = w2t + ((size_t)e * OUT_ + nbase + wn + i * 16 + lm) * H_ + lq * 8;
    }
    f32x4 acc[4][4] = {};
    bf16x8 abuf[2][4], bbuf[2][4];
#pragma unroll
    for (int i = 0; i < 4; i++) {
        abuf[0][i] = *(const bf16x8*)(ap[i]);
        bbuf[0][i] = *(const bf16x8*)(bp[i]);
        abuf[1][i] = *(const bf16x8*)(ap[i] + 32);
        bbuf[1][i] = *(const bf16x8*)(bp[i] + 32);
    }
#pragma unroll 4
    for (int k0 = 0; k0 < H_; k0 += 32) {
        int p = (k0 >> 5) & 1;
#pragma unroll
        for (int mi = 0; mi < 4; mi++)
#pragma unroll
            for (int ni = 0; ni < 4; ni++)
                acc[mi][ni] = __builtin_amdgcn_mfma_f32_16x16x32_bf16(abuf[p][mi], bbuf[p][ni], acc[mi][ni], 0, 0, 0);
        if (k0 + 64 < H_) {
#pragma unroll
            for (int i = 0; i < 4; i++) {
                abuf[p][i] = *(const bf16x8*)(ap[i] + k0 + 64);
                bbuf[p][i] = *(const bf16x8*)(bp[i] + k0 + 64);
            }
        }
    }
#pragma unroll
    for (int mi = 0; mi < 4; mi++) {
#pragma unroll
        for (int ni = 0; ni < 4; ni++) {
            int colg = nbase + wn + ni * 16 + lm;
            float bias = b2[e * OUT_ + colg];
#pragma unroll
            for (int r = 0; r < 4; r++) {
                int rowl = wm + mi * 16 + lq * 4 + r;
                eout[(size_t)(slot_base + rowl) * OUT_ + colg] = acc[mi][ni][r] + bias;
            }
        }
    }
}

// ---------------- combine + loss ----------------
__global__ __launch_bounds__(256) void k_combine(
    const float* __restrict__ eout, const int* __restrict__ rowslot,
    const float* __restrict__ top_gate, float* __restrict__ y,
    const float* __restrict__ partial_imp, const int* __restrict__ counts,
    float* __restrict__ loss_out) {
    int t = threadIdx.x;
    if (blockIdx.x == B_ / 4) {  // loss block
        __shared__ float imp[16];
        if (t < 16) {
            float s = 0.f;
#pragma unroll
            for (int b = 0; b < HBLK; b++) s += partial_imp[b * 16 + t];
            imp[t] = s;
        }
        __syncthreads();
        if (t == 0) {
            float si = 0.f, sl = 0.f;
            for (int e = 0; e < E_; e++) { si += imp[e]; sl += (float)counts[e]; }
            float mi_ = si / (float)E_, ml_ = sl / (float)E_;
            float vi = 0.f, vl = 0.f;
            for (int e = 0; e < E_; e++) {
                float d = imp[e] - mi_; vi += d * d;
                float d2 = (float)counts[e] - ml_; vl += d2 * d2;
            }
            vi /= (float)(E_ - 1); vl /= (float)(E_ - 1);
            *loss_out = vi / (mi_ * mi_ + 1e-10f) + vl / (ml_ * ml_ + 1e-10f);
        }
        return;
    }
    int b = blockIdx.x * 4 + (t >> 6);
    int lane = t & 63;
    int s0 = rowslot[b * 3], s1 = rowslot[b * 3 + 1], s2 = rowslot[b * 3 + 2];
    float g0 = top_gate[b * 3], g1 = top_gate[b * 3 + 1], g2 = top_gate[b * 3 + 2];
    const float4* e4 = (const float4*)eout;
    float4 v0 = e4[(size_t)s0 * 64 + lane];
    float4 v1 = e4[(size_t)s1 * 64 + lane];
    float4 v2 = e4[(size_t)s2 * 64 + lane];
    float4 r;
    r.x = g0 * v0.x + g1 * v1.x + g2 * v2.x;
    r.y = g0 * v0.y + g1 * v1.y + g2 * v2.y;
    r.z = g0 * v0.z + g1 * v1.z + g2 * v2.z;
    r.w = g0 * v0.w + g1 * v1.w + g2 * v2.w;
    ((float4*)y)[(size_t)b * 64 + lane] = r;
}

extern "C" void kernel_launch(void* const* d_in, const int* in_sizes, int n_in,
                              void* d_out, int out_size, void* d_ws, size_t ws_size,
                              hipStream_t stream) {
    (void)in_sizes; (void)n_in; (void)out_size; (void)ws_size;
    const float* x = (const float*)d_in[0];
    const float* wgate = (const float*)d_in[1];
    const float* W1 = (const float*)d_in[2];
    const float* b1 = (const float*)d_in[3];
    const float* W2 = (const float*)d_in[4];
    const float* b2 = (const float*)d_in[5];
    float* y = (float*)d_out;  // [B*OUT] floats, then loss scalar at [B*OUT]

    char* p = (char*)d_ws;
    auto alloc = [&](size_t bytes) {
        char* q = p;
        p += (bytes + 255) & ~(size_t)255;
        return q;
    };
    bf16* xbf = (bf16*)alloc((size_t)B_ * IN_ * 2);          // 16 MB (dead after gemm1)
    bf16* w1t = (bf16*)alloc((size_t)E_ * H_ * IN_ * 2);     // 16 MB (dead after gemm1)
    bf16* w2t = (bf16*)alloc((size_t)E_ * OUT_ * H_ * 2);    // 4 MB
    bf16* h = (bf16*)alloc((size_t)MAXSLOTS * H_ * 2);       // 27 MB
    int* row_ids = (int*)alloc((size_t)MAXSLOTS * 4);
    int* rowslot = (int*)alloc((size_t)B_ * KTOP * 4);
    int* top_idx = (int*)alloc((size_t)B_ * KTOP * 4);
    float* top_gate = (float*)alloc((size_t)B_ * KTOP * 4);
    int* counts = (int*)alloc(E_ * 4);
    float* partial_imp = (float*)alloc(HBLK * E_ * 4);
    int* tile_expert = (int*)alloc(NTILES * 4);
    // eout (27 MB f32) aliases xbf+w1t (32 MB): both dead after gemm1.
    float* eout = (float*)xbf;

    k_stage1<<<dim3(4713), dim3(256), 0, stream>>>(
        x, wgate, W1, W2, xbf, top_idx, top_gate, w1t, w2t, row_ids, tile_expert);
    k_dispatch<<<dim3(HBLK), dim3(256), 0, stream>>>(
        top_idx, top_gate, counts, tile_expert, row_ids, rowslot, partial_imp);
    k_gemm1<<<dim3(H_ / 128, NTILES), dim3(256), 0, stream>>>(
        xbf, w1t, b1, row_ids, tile_expert, h);
    k_gemm2<<<dim3(OUT_ / 128, NTILES), dim3(256), 0, stream>>>(
        h, w2t, b2, tile_expert, eout);
    k_combine<<<dim3(B_ / 4 + 1), dim3(256), 0, stream>>>(
        eout, rowslot, top_gate, y, partial_imp, counts, y + (size_t)B_ * OUT_);
}

// Round 9
// 219.437 us; speedup vs baseline: 1.5104x; 1.5104x over previous
//
#include <hip/hip_runtime.h>

#define B_ 8192
#define IN_ 1024
#define OUT_ 256
#define E_ 16
#define KTOP 3
#define H_ 512
#define MAXSLOTS 26624   // 24576 + 16*127 rounded up
#define NTILES 208       // MAXSLOTS / 128
#define HBLK 16          // hist/scatter blocks

typedef __bf16 bf16;
typedef __bf16 bf16x4 __attribute__((ext_vector_type(4)));
typedef __bf16 bf16x8 __attribute__((ext_vector_type(8)));
typedef float f32x4 __attribute__((ext_vector_type(4)));

// async global->LDS, 16B per lane. LDS dest must be wave-uniform base + lane*16.
__device__ __forceinline__ void async16(const bf16* g, bf16* l) {
    __builtin_amdgcn_global_load_lds(
        (const __attribute__((address_space(1))) void*)g,
        (__attribute__((address_space(3))) void*)l,
        16, 0, 0);
}

// ---------------- setup: W transposes + wgT + row_ids + zero_row + tile_expert ----------------
// blocks [0,2048): W1; [2048,2560): W2; [2560,2664): row_ids=-1; [2664,2728): wgT;
// 2728: zero_row + tile_expert=-1.
__global__ __launch_bounds__(256) void k_setup(
    const float* __restrict__ W1, bf16* __restrict__ w1t,
    const float* __restrict__ W2, bf16* __restrict__ w2t,
    int* __restrict__ row_ids, const float* __restrict__ wg, float* __restrict__ wgT,
    bf16* __restrict__ zero_row, int* __restrict__ tile_expert) {
    int bx = blockIdx.x;
    int t = threadIdx.x;
    if (bx >= 2560) {
        if (bx < 2664) {            // row_ids = -1 (104*256 == MAXSLOTS)
            row_ids[(bx - 2560) * 256 + t] = -1;
        } else if (bx < 2728) {     // wgT[e][j] = wg[j][e]
            int id = (bx - 2664) * 256 + t;
            int e = id >> 10, j = id & 1023;
            wgT[id] = wg[j * E_ + e];
        } else {                    // zero_row + tile_expert
#pragma unroll
            for (int i = 0; i < 4; i++) zero_row[t * 4 + i] = (bf16)0.f;
            if (t < NTILES) tile_expert[t] = -1;
        }
        return;
    }
    __shared__ float tile[64][65];
    const float* in; bf16* out; int Kd, Nd, e, tk, tn;
    if (bx < 2048) {            // W1: 16 experts x (16 x 8) tiles
        in = W1; out = w1t; Kd = IN_; Nd = H_;
        e = bx >> 7; int tt = bx & 127; tk = tt >> 3; tn = tt & 7;
    } else {                    // W2: 16 experts x (8 x 4) tiles
        int b2x = bx - 2048;
        in = W2; out = w2t; Kd = H_; Nd = OUT_;
        e = b2x >> 5; int tt = b2x & 31; tk = tt >> 2; tn = tt & 3;
    }
    int r = t >> 6, c = t & 63;
    const float* src = in + ((size_t)e * Kd + tk * 64) * Nd + (size_t)tn * 64;
#pragma unroll
    for (int i = 0; i < 16; i++) {
        int rr = r + i * 4;
        tile[rr][c] = src[(size_t)rr * Nd + c];
    }
    __syncthreads();
    bf16* dst = out + ((size_t)e * Nd + tn * 64) * Kd + (size_t)tk * 64;
#pragma unroll
    for (int i = 0; i < 16; i++) {
        int rr = r + i * 4;
        dst[(size_t)rr * Kd + c] = (bf16)tile[c][rr];
    }
}

// ---------------- gating: coalesced wgT reads, top-3 softmax, emit x as bf16 (R5-proven) ----------------
__global__ __launch_bounds__(256) void k_gating(
    const float* __restrict__ x, const float* __restrict__ wgT,
    bf16* __restrict__ xbf, int* __restrict__ top_idx, float* __restrict__ top_gate) {
    int t = threadIdx.x;
    int row = blockIdx.x * 4 + (t >> 6);
    int lane = t & 63;
    float acc[16];
#pragma unroll
    for (int e = 0; e < 16; e++) acc[e] = 0.f;
    const float4* x4p = (const float4*)(x + (size_t)row * IN_);
    const float4* w4 = (const float4*)wgT;
#pragma unroll
    for (int it = 0; it < 4; it++) {
        int j0 = it * 64 + lane;
        float4 xv = x4p[j0];
        bf16x4 xb;
        xb[0] = (bf16)xv.x; xb[1] = (bf16)xv.y; xb[2] = (bf16)xv.z; xb[3] = (bf16)xv.w;
        *(bf16x4*)(xbf + (size_t)row * IN_ + j0 * 4) = xb;
#pragma unroll
        for (int e = 0; e < 16; e++) {
            float4 wv = w4[e * 256 + j0];
            acc[e] += xv.x * wv.x + xv.y * wv.y + xv.z * wv.z + xv.w * wv.w;
        }
    }
#pragma unroll
    for (int e = 0; e < 16; e++) {
#pragma unroll
        for (int s = 32; s > 0; s >>= 1) acc[e] += __shfl_xor(acc[e], s, 64);
    }
    if (lane == 0) {
        float v[16];
#pragma unroll
        for (int e = 0; e < 16; e++) v[e] = acc[e];
        int idx[KTOP];
        float val[KTOP];
#pragma unroll
        for (int k = 0; k < KTOP; k++) {
            int best = 0;
            float bv = v[0];
            for (int e = 1; e < 16; e++) {
                if (v[e] > bv) { bv = v[e]; best = e; }
            }
            idx[k] = best; val[k] = bv; v[best] = -1e30f;
        }
        float e1 = __expf(val[1] - val[0]);
        float e2 = __expf(val[2] - val[0]);
        float inv = 1.f / (1.f + e1 + e2);
        float g[KTOP] = {inv, e1 * inv, e2 * inv};
#pragma unroll
        for (int k = 0; k < KTOP; k++) {
            top_idx[row * KTOP + k] = idx[k];
            top_gate[row * KTOP + k] = g[k];
        }
    }
}

// ---------------- hist: 16 blocks, ballot histogram, zero atomics (R5-proven) ----------------
__global__ __launch_bounds__(256) void k_hist(
    const int* __restrict__ top_idx, int* __restrict__ partial) {
    __shared__ int wcnt[4][16];
    int t = threadIdx.x;
    int w = t >> 6, lane = t & 63;
    int blk = blockIdx.x;
    int cnt[16];
#pragma unroll
    for (int k = 0; k < 16; k++) cnt[k] = 0;
#pragma unroll
    for (int j = 0; j < 6; j++) {
        int e = top_idx[blk * 1536 + j * 256 + t];
#pragma unroll
        for (int k = 0; k < 16; k++)
            cnt[k] += (int)__popcll(__ballot(e == k));
    }
    if (lane == 0) {
#pragma unroll
        for (int k = 0; k < 16; k++) wcnt[w][k] = cnt[k];
    }
    __syncthreads();
    if (t < 16) partial[blk * 16 + t] = wcnt[0][t] + wcnt[1][t] + wcnt[2][t] + wcnt[3][t];
}

// ---------------- scan: counts, padded offsets, tile map, per-(block,expert) bases ----------------
__global__ __launch_bounds__(256) void k_scan(
    const int* __restrict__ partial, int* __restrict__ counts,
    int* __restrict__ tile_expert, int* __restrict__ gbase) {
    __shared__ int sp[HBLK * 16];
    __shared__ int soff[16];
    int t = threadIdx.x;
    sp[t] = partial[t];
    __syncthreads();
    if (t < 16) {
        int s = 0;
#pragma unroll
        for (int b = 0; b < HBLK; b++) s += sp[b * 16 + t];
        counts[t] = s;
    }
    __syncthreads();
    if (t == 0) {
        int off = 0;
        for (int e = 0; e < E_; e++) {
            int c = 0;
#pragma unroll
            for (int b = 0; b < HBLK; b++) c += sp[b * 16 + e];
            soff[e] = off;
            int pd = (c + 127) & ~127;
            int t0 = off >> 7, t1 = (off + pd) >> 7;
            for (int tt = t0; tt < t1; ++tt) tile_expert[tt] = e;
            off += pd;
        }
    }
    __syncthreads();
    {   // gbase[b][e] = soff[e] + sum_{b'<b} partial[b'][e]
        int b = t >> 4, e = t & 15;
        int s = soff[e];
        for (int bp = 0; bp < b; bp++) s += sp[bp * 16 + e];
        gbase[t] = s;
    }
}

// ---------------- scatter: LDS-rank only (zero global atomics), partial importance ----------------
__global__ __launch_bounds__(256) void k_scatter(
    const int* __restrict__ top_idx, const float* __restrict__ top_gate,
    const int* __restrict__ gbase,
    int* __restrict__ row_ids, int* __restrict__ rowslot,
    float* __restrict__ partial_imp) {
    __shared__ int lcnt[16];
    __shared__ float limp[16];
    int t = threadIdx.x;
    int blk = blockIdx.x;
    if (t < 16) { lcnt[t] = 0; limp[t] = 0.f; }
    __syncthreads();
#pragma unroll
    for (int j = 0; j < 6; j++) {
        int gid = blk * 1536 + j * 256 + t;
        int e = top_idx[gid];
        float g = top_gate[gid];
        int rank = atomicAdd(&lcnt[e], 1);
        atomicAdd(&limp[e], g);
        int slot = gbase[blk * 16 + e] + rank;
        row_ids[slot] = gid / KTOP;
        rowslot[gid] = slot;
    }
    __syncthreads();
    if (t < 16) partial_imp[blk * 16 + t] = limp[t];
}

// ---------------- GEMM1: R5-proven exactly (BK=64, XOR swizzle, grid n-fast) ----------------
__global__ __launch_bounds__(256) void k_gemm1(
    const bf16* __restrict__ xbf, const bf16* __restrict__ w1t,
    const float* __restrict__ b1, const int* __restrict__ row_ids,
    const int* __restrict__ tile_expert, const bf16* __restrict__ zero_row,
    bf16* __restrict__ h) {
    int e = tile_expert[blockIdx.y];
    if (e < 0) return;
    int slot_base = blockIdx.y * 128;
    int nbase = blockIdx.x * 128;
    __shared__ __align__(16) bf16 As[128 * 64];  // 16 KB
    __shared__ __align__(16) bf16 Bs[128 * 64];  // 16 KB
    int t = threadIdx.x;
    int rmod = (t >> 3) & 7;
    int cglob = (t & 7) ^ rmod;
    const bf16* gA[4];
    const bf16* gB[4];
#pragma unroll
    for (int j = 0; j < 4; j++) {
        int m = j * 32 + (t >> 3);
        int rid = row_ids[slot_base + m];
        gA[j] = ((rid >= 0) ? xbf + (size_t)rid * IN_ : zero_row) + cglob * 8;
        gB[j] = w1t + ((size_t)e * H_ + nbase + m) * IN_ + cglob * 8;
    }
    int w = t >> 6, lane = t & 63;
    int wm = (w >> 1) * 64, wn = (w & 1) * 64;
    int lm = lane & 15, lq = lane >> 4;
    f32x4 acc[4][4] = {};
    for (int k0 = 0; k0 < IN_; k0 += 64) {
#pragma unroll
        for (int j = 0; j < 4; j++) {
            async16(gA[j] + k0, As + (j * 256 + t) * 8);
            async16(gB[j] + k0, Bs + (j * 256 + t) * 8);
        }
        __syncthreads();
        const bf16x8* Av = (const bf16x8*)As;
        const bf16x8* Bv = (const bf16x8*)Bs;
#pragma unroll
        for (int ks = 0; ks < 2; ks++) {
            int kc = ks * 4 + lq;
            bf16x8 af[4], bfv[4];
#pragma unroll
            for (int i = 0; i < 4; i++) {
                int row = wm + i * 16 + lm;
                af[i] = Av[row * 8 + (kc ^ (row & 7))];
            }
#pragma unroll
            for (int i = 0; i < 4; i++) {
                int row = wn + i * 16 + lm;
                bfv[i] = Bv[row * 8 + (kc ^ (row & 7))];
            }
#pragma unroll
            for (int mi = 0; mi < 4; mi++)
#pragma unroll
                for (int ni = 0; ni < 4; ni++)
                    acc[mi][ni] = __builtin_amdgcn_mfma_f32_16x16x32_bf16(af[mi], bfv[ni], acc[mi][ni], 0, 0, 0);
        }
        __syncthreads();
    }
#pragma unroll
    for (int mi = 0; mi < 4; mi++) {
#pragma unroll
        for (int ni = 0; ni < 4; ni++) {
            int colg = nbase + wn + ni * 16 + lm;
            float bias = b1[e * H_ + colg];
#pragma unroll
            for (int r = 0; r < 4; r++) {
                int rowl = wm + mi * 16 + lq * 4 + r;
                float v = acc[mi][ni][r] + bias;
                v = v > 0.f ? v : 0.f;
                h[(size_t)(slot_base + rowl) * H_ + colg] = (bf16)v;
            }
        }
    }
}

// ---------------- GEMM2: BN=256 (one block/tile), bf16 eout output ----------------
__global__ __launch_bounds__(256) void k_gemm2(
    const bf16* __restrict__ h, const bf16* __restrict__ w2t,
    const float* __restrict__ b2, const int* __restrict__ tile_expert,
    bf16* __restrict__ eout) {
    int e = tile_expert[blockIdx.x];
    if (e < 0) return;
    int slot_base = blockIdx.x * 128;
    __shared__ __align__(16) bf16 As[128 * 64];   // 16 KB
    __shared__ __align__(16) bf16 Bs[256 * 64];   // 32 KB
    int t = threadIdx.x;
    int rmod = (t >> 3) & 7;
    int cglob = (t & 7) ^ rmod;
    const bf16* gA[4];
    const bf16* gB[8];
#pragma unroll
    for (int j = 0; j < 4; j++) {
        int m = j * 32 + (t >> 3);
        gA[j] = h + (size_t)(slot_base + m) * H_ + cglob * 8;
    }
#pragma unroll
    for (int j = 0; j < 8; j++) {
        int m = j * 32 + (t >> 3);
        gB[j] = w2t + ((size_t)e * OUT_ + m) * H_ + cglob * 8;
    }
    int w = t >> 6, lane = t & 63;
    int wm = (w >> 1) * 64, wn = (w & 1) * 128;
    int lm = lane & 15, lq = lane >> 4;
    f32x4 acc[4][8] = {};
    for (int k0 = 0; k0 < H_; k0 += 64) {
#pragma unroll
        for (int j = 0; j < 4; j++) async16(gA[j] + k0, As + (j * 256 + t) * 8);
#pragma unroll
        for (int j = 0; j < 8; j++) async16(gB[j] + k0, Bs + (j * 256 + t) * 8);
        __syncthreads();
        const bf16x8* Av = (const bf16x8*)As;
        const bf16x8* Bv = (const bf16x8*)Bs;
#pragma unroll
        for (int ks = 0; ks < 2; ks++) {
            int kc = ks * 4 + lq;
            bf16x8 af[4], bfv[8];
#pragma unroll
            for (int i = 0; i < 4; i++) {
                int row = wm + i * 16 + lm;
                af[i] = Av[row * 8 + (kc ^ (row & 7))];
            }
#pragma unroll
            for (int i = 0; i < 8; i++) {
                int row = wn + i * 16 + lm;
                bfv[i] = Bv[row * 8 + (kc ^ (row & 7))];
            }
#pragma unroll
            for (int mi = 0; mi < 4; mi++)
#pragma unroll
                for (int ni = 0; ni < 8; ni++)
                    acc[mi][ni] = __builtin_amdgcn_mfma_f32_16x16x32_bf16(af[mi], bfv[ni], acc[mi][ni], 0, 0, 0);
        }
        __syncthreads();
    }
#pragma unroll
    for (int mi = 0; mi < 4; mi++) {
#pragma unroll
        for (int ni = 0; ni < 8; ni++) {
            int colg = wn + ni * 16 + lm;
            float bias = b2[e * OUT_ + colg];
#pragma unroll
            for (int r = 0; r < 4; r++) {
                int rowl = wm + mi * 16 + lq * 4 + r;
                eout[(size_t)(slot_base + rowl) * OUT_ + colg] = (bf16)(acc[mi][ni][r] + bias);
            }
        }
    }
}

// ---------------- combine + loss: y[b] = sum_k gate_k * eout[slot_k]; block B_/4 does loss ----------------
__global__ __launch_bounds__(256) void k_combine(
    const bf16* __restrict__ eout, const int* __restrict__ rowslot,
    const float* __restrict__ top_gate, float* __restrict__ y,
    const float* __restrict__ partial_imp, const int* __restrict__ counts,
    float* __restrict__ loss_out) {
    int t = threadIdx.x;
    if (blockIdx.x == B_ / 4) {  // loss block
        __shared__ float imp[16];
        if (t < 16) {
            float s = 0.f;
#pragma unroll
            for (int b = 0; b < HBLK; b++) s += partial_imp[b * 16 + t];
            imp[t] = s;
        }
        __syncthreads();
        if (t == 0) {
            float si = 0.f, sl = 0.f;
            for (int e = 0; e < E_; e++) { si += imp[e]; sl += (float)counts[e]; }
            float mi_ = si / (float)E_, ml_ = sl / (float)E_;
            float vi = 0.f, vl = 0.f;
            for (int e = 0; e < E_; e++) {
                float d = imp[e] - mi_; vi += d * d;
                float d2 = (float)counts[e] - ml_; vl += d2 * d2;
            }
            vi /= (float)(E_ - 1); vl /= (float)(E_ - 1);
            *loss_out = vi / (mi_ * mi_ + 1e-10f) + vl / (ml_ * ml_ + 1e-10f);
        }
        return;
    }
    int b = blockIdx.x * 4 + (t >> 6);
    int lane = t & 63;
    int s0 = rowslot[b * 3], s1 = rowslot[b * 3 + 1], s2 = rowslot[b * 3 + 2];
    float g0 = top_gate[b * 3], g1 = top_gate[b * 3 + 1], g2 = top_gate[b * 3 + 2];
    bf16x4 v0 = *(const bf16x4*)(eout + (size_t)s0 * OUT_ + lane * 4);
    bf16x4 v1 = *(const bf16x4*)(eout + (size_t)s1 * OUT_ + lane * 4);
    bf16x4 v2 = *(const bf16x4*)(eout + (size_t)s2 * OUT_ + lane * 4);
    float4 r;
    r.x = g0 * (float)v0[0] + g1 * (float)v1[0] + g2 * (float)v2[0];
    r.y = g0 * (float)v0[1] + g1 * (float)v1[1] + g2 * (float)v2[1];
    r.z = g0 * (float)v0[2] + g1 * (float)v1[2] + g2 * (float)v2[2];
    r.w = g0 * (float)v0[3] + g1 * (float)v1[3] + g2 * (float)v2[3];
    ((float4*)y)[(size_t)b * 64 + lane] = r;
}

extern "C" void kernel_launch(void* const* d_in, const int* in_sizes, int n_in,
                              void* d_out, int out_size, void* d_ws, size_t ws_size,
                              hipStream_t stream) {
    (void)in_sizes; (void)n_in; (void)out_size; (void)ws_size;
    const float* x = (const float*)d_in[0];
    const float* wgate = (const float*)d_in[1];
    const float* W1 = (const float*)d_in[2];
    const float* b1 = (const float*)d_in[3];
    const float* W2 = (const float*)d_in[4];
    const float* b2 = (const float*)d_in[5];
    float* y = (float*)d_out;  // [B*OUT] floats, then loss scalar at [B*OUT]

    char* p = (char*)d_ws;
    auto alloc = [&](size_t bytes) {
        char* q = p;
        p += (bytes + 255) & ~(size_t)255;
        return q;
    };
    bf16* xbf = (bf16*)alloc((size_t)B_ * IN_ * 2);          // 16 MB (dead after gemm1)
    bf16* w1t = (bf16*)alloc((size_t)E_ * H_ * IN_ * 2);     // 16 MB (dead after gemm1)
    bf16* w2t = (bf16*)alloc((size_t)E_ * OUT_ * H_ * 2);    // 4 MB
    bf16* h = (bf16*)alloc((size_t)MAXSLOTS * H_ * 2);       // 27 MB
    int* row_ids = (int*)alloc((size_t)MAXSLOTS * 4);
    int* rowslot = (int*)alloc((size_t)B_ * KTOP * 4);
    int* top_idx = (int*)alloc((size_t)B_ * KTOP * 4);
    float* top_gate = (float*)alloc((size_t)B_ * KTOP * 4);
    int* counts = (int*)alloc(E_ * 4);
    int* partial = (int*)alloc(HBLK * E_ * 4);
    int* gbase = (int*)alloc(HBLK * E_ * 4);
    float* partial_imp = (float*)alloc(HBLK * E_ * 4);
    int* tile_expert = (int*)alloc(NTILES * 4);
    bf16* zero_row = (bf16*)alloc(IN_ * 2);
    float* wgT = (float*)alloc((size_t)E_ * IN_ * 4);        // 64 KB
    // eout (13.5 MB bf16) aliases xbf (16 MB): xbf dead after gemm1.
    bf16* eout = (bf16*)xbf;

    k_setup<<<dim3(2729), dim3(256), 0, stream>>>(
        W1, w1t, W2, w2t, row_ids, wgate, wgT, zero_row, tile_expert);
    k_gating<<<dim3(B_ / 4), dim3(256), 0, stream>>>(x, wgT, xbf, top_idx, top_gate);
    k_hist<<<dim3(HBLK), dim3(256), 0, stream>>>(top_idx, partial);
    k_scan<<<dim3(1), dim3(256), 0, stream>>>(partial, counts, tile_expert, gbase);
    k_scatter<<<dim3(HBLK), dim3(256), 0, stream>>>(
        top_idx, top_gate, gbase, row_ids, rowslot, partial_imp);
    k_gemm1<<<dim3(H_ / 128, NTILES), dim3(256), 0, stream>>>(
        xbf, w1t, b1, row_ids, tile_expert, zero_row, h);
    k_gemm2<<<dim3(NTILES), dim3(256), 0, stream>>>(
        h, w2t, b2, tile_expert, eout);
    k_combine<<<dim3(B_ / 4 + 1), dim3(256), 0, stream>>>(
        eout, rowslot, top_gate, y, partial_imp, counts, y + (size_t)B_ * OUT_);
}

// Round 10
// 212.403 us; speedup vs baseline: 1.5605x; 1.0331x over previous
//
#include <hip/hip_runtime.h>

#define B_ 8192
#define IN_ 1024
#define OUT_ 256
#define E_ 16
#define KTOP 3
#define H_ 512
#define MAXSLOTS 26624   // 24576 + 16*127 rounded up
#define NTILES 208       // MAXSLOTS / 128
#define HBLK 16          // scatterscan blocks
#define GBLK 2048        // gating blocks

typedef __bf16 bf16;
typedef __bf16 bf16x4 __attribute__((ext_vector_type(4)));
typedef __bf16 bf16x8 __attribute__((ext_vector_type(8)));
typedef float f32x4 __attribute__((ext_vector_type(4)));

// async global->LDS, 16B per lane. LDS dest must be wave-uniform base + lane*16.
__device__ __forceinline__ void async16(const bf16* g, bf16* l) {
    __builtin_amdgcn_global_load_lds(
        (const __attribute__((address_space(1))) void*)g,
        (__attribute__((address_space(3))) void*)l,
        16, 0, 0);
}

// ---------------- setup: W transposes + wgT + row_ids + zero_row + tile_expert ----------------
// blocks [0,2048): W1; [2048,2560): W2; [2560,2664): row_ids=-1; [2664,2728): wgT;
// 2728: zero_row + tile_expert=-1.
__global__ __launch_bounds__(256) void k_setup(
    const float* __restrict__ W1, bf16* __restrict__ w1t,
    const float* __restrict__ W2, bf16* __restrict__ w2t,
    int* __restrict__ row_ids, const float* __restrict__ wg, float* __restrict__ wgT,
    bf16* __restrict__ zero_row, int* __restrict__ tile_expert) {
    int bx = blockIdx.x;
    int t = threadIdx.x;
    if (bx >= 2560) {
        if (bx < 2664) {            // row_ids = -1 (104*256 == MAXSLOTS)
            row_ids[(bx - 2560) * 256 + t] = -1;
        } else if (bx < 2728) {     // wgT[e][j] = wg[j][e]
            int id = (bx - 2664) * 256 + t;
            int e = id >> 10, j = id & 1023;
            wgT[id] = wg[j * E_ + e];
        } else {                    // zero_row + tile_expert
#pragma unroll
            for (int i = 0; i < 4; i++) zero_row[t * 4 + i] = (bf16)0.f;
            if (t < NTILES) tile_expert[t] = -1;
        }
        return;
    }
    __shared__ float tile[64][65];
    const float* in; bf16* out; int Kd, Nd, e, tk, tn;
    if (bx < 2048) {            // W1: 16 experts x (16 x 8) tiles
        in = W1; out = w1t; Kd = IN_; Nd = H_;
        e = bx >> 7; int tt = bx & 127; tk = tt >> 3; tn = tt & 7;
    } else {                    // W2: 16 experts x (8 x 4) tiles
        int b2x = bx - 2048;
        in = W2; out = w2t; Kd = H_; Nd = OUT_;
        e = b2x >> 5; int tt = b2x & 31; tk = tt >> 2; tn = tt & 3;
    }
    int r = t >> 6, c = t & 63;
    const float* src = in + ((size_t)e * Kd + tk * 64) * Nd + (size_t)tn * 64;
#pragma unroll
    for (int i = 0; i < 16; i++) {
        int rr = r + i * 4;
        tile[rr][c] = src[(size_t)rr * Nd + c];
    }
    __syncthreads();
    bf16* dst = out + ((size_t)e * Nd + tn * 64) * Kd + (size_t)tk * 64;
#pragma unroll
    for (int i = 0; i < 16; i++) {
        int rr = r + i * 4;
        dst[(size_t)rr * Kd + c] = (bf16)tile[c][rr];
    }
}

// ---------------- gating: coalesced wgT reads, top-3 softmax, emit x bf16 + per-block hist ----------------
__global__ __launch_bounds__(256) void k_gating(
    const float* __restrict__ x, const float* __restrict__ wgT,
    bf16* __restrict__ xbf, int* __restrict__ top_idx, float* __restrict__ top_gate,
    int* __restrict__ partial) {
    __shared__ int lcnt[16];
    int t = threadIdx.x;
    int row = blockIdx.x * 4 + (t >> 6);
    int lane = t & 63;
    if (t < 16) lcnt[t] = 0;
    __syncthreads();
    float acc[16];
#pragma unroll
    for (int e = 0; e < 16; e++) acc[e] = 0.f;
    const float4* x4p = (const float4*)(x + (size_t)row * IN_);
    const float4* w4 = (const float4*)wgT;
#pragma unroll
    for (int it = 0; it < 4; it++) {
        int j0 = it * 64 + lane;
        float4 xv = x4p[j0];
        bf16x4 xb;
        xb[0] = (bf16)xv.x; xb[1] = (bf16)xv.y; xb[2] = (bf16)xv.z; xb[3] = (bf16)xv.w;
        *(bf16x4*)(xbf + (size_t)row * IN_ + j0 * 4) = xb;
#pragma unroll
        for (int e = 0; e < 16; e++) {
            float4 wv = w4[e * 256 + j0];
            acc[e] += xv.x * wv.x + xv.y * wv.y + xv.z * wv.z + xv.w * wv.w;
        }
    }
#pragma unroll
    for (int e = 0; e < 16; e++) {
#pragma unroll
        for (int s = 32; s > 0; s >>= 1) acc[e] += __shfl_xor(acc[e], s, 64);
    }
    if (lane == 0) {
        float v[16];
#pragma unroll
        for (int e = 0; e < 16; e++) v[e] = acc[e];
        int idx[KTOP];
        float val[KTOP];
#pragma unroll
        for (int k = 0; k < KTOP; k++) {
            int best = 0;
            float bv = v[0];
            for (int e = 1; e < 16; e++) {
                if (v[e] > bv) { bv = v[e]; best = e; }
            }
            idx[k] = best; val[k] = bv; v[best] = -1e30f;
        }
        float e1 = __expf(val[1] - val[0]);
        float e2 = __expf(val[2] - val[0]);
        float inv = 1.f / (1.f + e1 + e2);
        float g[KTOP] = {inv, e1 * inv, e2 * inv};
#pragma unroll
        for (int k = 0; k < KTOP; k++) {
            top_idx[row * KTOP + k] = idx[k];
            top_gate[row * KTOP + k] = g[k];
            atomicAdd(&lcnt[idx[k]], 1);
        }
    }
    __syncthreads();
    if (t < 16) partial[blockIdx.x * 16 + t] = lcnt[t];
}

// ---------------- scatterscan: scan of 2048x16 partials + scatter, 16 blocks, zero global atomics ----------------
// Block b covers gids [b*1536,(b+1)*1536) == gating blocks [b*128,(b+1)*128) == segment b.
__global__ __launch_bounds__(256) void k_scatterscan(
    const int* __restrict__ top_idx, const float* __restrict__ top_gate,
    const int* __restrict__ partial,
    int* __restrict__ counts, int* __restrict__ tile_expert,
    int* __restrict__ row_ids, int* __restrict__ rowslot,
    float* __restrict__ partial_imp) {
    __shared__ int segsum[16][16];   // [seg][e]
    __shared__ int tote[16];
    __shared__ int sbase[16];
    __shared__ int lcnt[16];
    __shared__ float limp[16];
    int t = threadIdx.x;
    int blk = blockIdx.x;
    int e = t & 15, seg = t >> 4;    // 16 segs x 128 gating-chunks each
    int s = 0;
    for (int i = 0; i < 128; i++) s += partial[(seg * 128 + i) * 16 + e];
    segsum[seg][e] = s;
    if (t < 16) { lcnt[t] = 0; limp[t] = 0.f; }
    __syncthreads();
    if (t < 16) {
        int total = 0, pre = 0;
        for (int sg = 0; sg < 16; sg++) {
            int v = segsum[sg][t];
            total += v;
            if (sg < blk) pre += v;
        }
        tote[t] = total;
        segsum[0][t] = pre;          // stash pre (segsum row 0 no longer needed as-is after tote)
    }
    __syncthreads();
    if (t < 16) {
        int off = 0;
        for (int ee = 0; ee < 16; ee++) {
            if (ee == t) break;
            off += (tote[ee] + 127) & ~127;
        }
        sbase[t] = off + segsum[0][t];
        if (blk == 0) {
            counts[t] = tote[t];
            int pd = (tote[t] + 127) & ~127;
            for (int tt = off >> 7; tt < (off + pd) >> 7; ++tt) tile_expert[tt] = t;
        }
    }
    __syncthreads();
#pragma unroll
    for (int j = 0; j < 6; j++) {
        int gid = blk * 1536 + j * 256 + t;
        int ee = top_idx[gid];
        float g = top_gate[gid];
        int rank = atomicAdd(&lcnt[ee], 1);
        atomicAdd(&limp[ee], g);
        int slot = sbase[ee] + rank;
        row_ids[slot] = gid / KTOP;
        rowslot[gid] = slot;
    }
    __syncthreads();
    if (t < 16) partial_imp[blk * 16 + t] = limp[t];
}

// ---------------- GEMM1: R5-proven exactly (BK=64, XOR swizzle, grid n-fast) ----------------
__global__ __launch_bounds__(256) void k_gemm1(
    const bf16* __restrict__ xbf, const bf16* __restrict__ w1t,
    const float* __restrict__ b1, const int* __restrict__ row_ids,
    const int* __restrict__ tile_expert, const bf16* __restrict__ zero_row,
    bf16* __restrict__ h) {
    int e = tile_expert[blockIdx.y];
    if (e < 0) return;
    int slot_base = blockIdx.y * 128;
    int nbase = blockIdx.x * 128;
    __shared__ __align__(16) bf16 As[128 * 64];  // 16 KB
    __shared__ __align__(16) bf16 Bs[128 * 64];  // 16 KB
    int t = threadIdx.x;
    int rmod = (t >> 3) & 7;
    int cglob = (t & 7) ^ rmod;
    const bf16* gA[4];
    const bf16* gB[4];
#pragma unroll
    for (int j = 0; j < 4; j++) {
        int m = j * 32 + (t >> 3);
        int rid = row_ids[slot_base + m];
        gA[j] = ((rid >= 0) ? xbf + (size_t)rid * IN_ : zero_row) + cglob * 8;
        gB[j] = w1t + ((size_t)e * H_ + nbase + m) * IN_ + cglob * 8;
    }
    int w = t >> 6, lane = t & 63;
    int wm = (w >> 1) * 64, wn = (w & 1) * 64;
    int lm = lane & 15, lq = lane >> 4;
    f32x4 acc[4][4] = {};
    for (int k0 = 0; k0 < IN_; k0 += 64) {
#pragma unroll
        for (int j = 0; j < 4; j++) {
            async16(gA[j] + k0, As + (j * 256 + t) * 8);
            async16(gB[j] + k0, Bs + (j * 256 + t) * 8);
        }
        __syncthreads();
        const bf16x8* Av = (const bf16x8*)As;
        const bf16x8* Bv = (const bf16x8*)Bs;
#pragma unroll
        for (int ks = 0; ks < 2; ks++) {
            int kc = ks * 4 + lq;
            bf16x8 af[4], bfv[4];
#pragma unroll
            for (int i = 0; i < 4; i++) {
                int row = wm + i * 16 + lm;
                af[i] = Av[row * 8 + (kc ^ (row & 7))];
            }
#pragma unroll
            for (int i = 0; i < 4; i++) {
                int row = wn + i * 16 + lm;
                bfv[i] = Bv[row * 8 + (kc ^ (row & 7))];
            }
#pragma unroll
            for (int mi = 0; mi < 4; mi++)
#pragma unroll
                for (int ni = 0; ni < 4; ni++)
                    acc[mi][ni] = __builtin_amdgcn_mfma_f32_16x16x32_bf16(af[mi], bfv[ni], acc[mi][ni], 0, 0, 0);
        }
        __syncthreads();
    }
#pragma unroll
    for (int mi = 0; mi < 4; mi++) {
#pragma unroll
        for (int ni = 0; ni < 4; ni++) {
            int colg = nbase + wn + ni * 16 + lm;
            float bias = b1[e * H_ + colg];
#pragma unroll
            for (int r = 0; r < 4; r++) {
                int rowl = wm + mi * 16 + lq * 4 + r;
                float v = acc[mi][ni][r] + bias;
                v = v > 0.f ? v : 0.f;
                h[(size_t)(slot_base + rowl) * H_ + colg] = (bf16)v;
            }
        }
    }
}

// ---------------- GEMM2: BN=256 (one block/tile), bf16 eout output ----------------
__global__ __launch_bounds__(256) void k_gemm2(
    const bf16* __restrict__ h, const bf16* __restrict__ w2t,
    const float* __restrict__ b2, const int* __restrict__ tile_expert,
    bf16* __restrict__ eout) {
    int e = tile_expert[blockIdx.x];
    if (e < 0) return;
    int slot_base = blockIdx.x * 128;
    __shared__ __align__(16) bf16 As[128 * 64];   // 16 KB
    __shared__ __align__(16) bf16 Bs[256 * 64];   // 32 KB
    int t = threadIdx.x;
    int rmod = (t >> 3) & 7;
    int cglob = (t & 7) ^ rmod;
    const bf16* gA[4];
    const bf16* gB[8];
#pragma unroll
    for (int j = 0; j < 4; j++) {
        int m = j * 32 + (t >> 3);
        gA[j] = h + (size_t)(slot_base + m) * H_ + cglob * 8;
    }
#pragma unroll
    for (int j = 0; j < 8; j++) {
        int m = j * 32 + (t >> 3);
        gB[j] = w2t + ((size_t)e * OUT_ + m) * H_ + cglob * 8;
    }
    int w = t >> 6, lane = t & 63;
    int wm = (w >> 1) * 64, wn = (w & 1) * 128;
    int lm = lane & 15, lq = lane >> 4;
    f32x4 acc[4][8] = {};
    for (int k0 = 0; k0 < H_; k0 += 64) {
#pragma unroll
        for (int j = 0; j < 4; j++) async16(gA[j] + k0, As + (j * 256 + t) * 8);
#pragma unroll
        for (int j = 0; j < 8; j++) async16(gB[j] + k0, Bs + (j * 256 + t) * 8);
        __syncthreads();
        const bf16x8* Av = (const bf16x8*)As;
        const bf16x8* Bv = (const bf16x8*)Bs;
#pragma unroll
        for (int ks = 0; ks < 2; ks++) {
            int kc = ks * 4 + lq;
            bf16x8 af[4], bfv[8];
#pragma unroll
            for (int i = 0; i < 4; i++) {
                int row = wm + i * 16 + lm;
                af[i] = Av[row * 8 + (kc ^ (row & 7))];
            }
#pragma unroll
            for (int i = 0; i < 8; i++) {
                int row = wn + i * 16 + lm;
                bfv[i] = Bv[row * 8 + (kc ^ (row & 7))];
            }
#pragma unroll
            for (int mi = 0; mi < 4; mi++)
#pragma unroll
                for (int ni = 0; ni < 8; ni++)
                    acc[mi][ni] = __builtin_amdgcn_mfma_f32_16x16x32_bf16(af[mi], bfv[ni], acc[mi][ni], 0, 0, 0);
        }
        __syncthreads();
    }
#pragma unroll
    for (int mi = 0; mi < 4; mi++) {
#pragma unroll
        for (int ni = 0; ni < 8; ni++) {
            int colg = wn + ni * 16 + lm;
            float bias = b2[e * OUT_ + colg];
#pragma unroll
            for (int r = 0; r < 4; r++) {
                int rowl = wm + mi * 16 + lq * 4 + r;
                eout[(size_t)(slot_base + rowl) * OUT_ + colg] = (bf16)(acc[mi][ni][r] + bias);
            }
        }
    }
}

// ---------------- combine + loss: y[b] = sum_k gate_k * eout[slot_k]; block B_/4 does loss ----------------
__global__ __launch_bounds__(256) void k_combine(
    const bf16* __restrict__ eout, const int* __restrict__ rowslot,
    const float* __restrict__ top_gate, float* __restrict__ y,
    const float* __restrict__ partial_imp, const int* __restrict__ counts,
    float* __restrict__ loss_out) {
    int t = threadIdx.x;
    if (blockIdx.x == B_ / 4) {  // loss block
        __shared__ float imp[16];
        if (t < 16) {
            float s = 0.f;
#pragma unroll
            for (int b = 0; b < HBLK; b++) s += partial_imp[b * 16 + t];
            imp[t] = s;
        }
        __syncthreads();
        if (t == 0) {
            float si = 0.f, sl = 0.f;
            for (int e = 0; e < E_; e++) { si += imp[e]; sl += (float)counts[e]; }
            float mi_ = si / (float)E_, ml_ = sl / (float)E_;
            float vi = 0.f, vl = 0.f;
            for (int e = 0; e < E_; e++) {
                float d = imp[e] - mi_; vi += d * d;
                float d2 = (float)counts[e] - ml_; vl += d2 * d2;
            }
            vi /= (float)(E_ - 1); vl /= (float)(E_ - 1);
            *loss_out = vi / (mi_ * mi_ + 1e-10f) + vl / (ml_ * ml_ + 1e-10f);
        }
        return;
    }
    int b = blockIdx.x * 4 + (t >> 6);
    int lane = t & 63;
    int s0 = rowslot[b * 3], s1 = rowslot[b * 3 + 1], s2 = rowslot[b * 3 + 2];
    float g0 = top_gate[b * 3], g1 = top_gate[b * 3 + 1], g2 = top_gate[b * 3 + 2];
    bf16x4 v0 = *(const bf16x4*)(eout + (size_t)s0 * OUT_ + lane * 4);
    bf16x4 v1 = *(const bf16x4*)(eout + (size_t)s1 * OUT_ + lane * 4);
    bf16x4 v2 = *(const bf16x4*)(eout + (size_t)s2 * OUT_ + lane * 4);
    float4 r;
    r.x = g0 * (float)v0[0] + g1 * (float)v1[0] + g2 * (float)v2[0];
    r.y = g0 * (float)v0[1] + g1 * (float)v1[1] + g2 * (float)v2[1];
    r.z = g0 * (float)v0[2] + g1 * (float)v1[2] + g2 * (float)v2[2];
    r.w = g0 * (float)v0[3] + g1 * (float)v1[3] + g2 * (float)v2[3];
    ((float4*)y)[(size_t)b * 64 + lane] = r;
}

extern "C" void kernel_launch(void* const* d_in, const int* in_sizes, int n_in,
                              void* d_out, int out_size, void* d_ws, size_t ws_size,
                              hipStream_t stream) {
    (void)in_sizes; (void)n_in; (void)out_size; (void)ws_size;
    const float* x = (const float*)d_in[0];
    const float* wgate = (const float*)d_in[1];
    const float* W1 = (const float*)d_in[2];
    const float* b1 = (const float*)d_in[3];
    const float* W2 = (const float*)d_in[4];
    const float* b2 = (const float*)d_in[5];
    float* y = (float*)d_out;  // [B*OUT] floats, then loss scalar at [B*OUT]

    char* p = (char*)d_ws;
    auto alloc = [&](size_t bytes) {
        char* q = p;
        p += (bytes + 255) & ~(size_t)255;
        return q;
    };
    bf16* xbf = (bf16*)alloc((size_t)B_ * IN_ * 2);          // 16 MB (dead after gemm1)
    bf16* w1t = (bf16*)alloc((size_t)E_ * H_ * IN_ * 2);     // 16 MB (dead after gemm1)
    bf16* w2t = (bf16*)alloc((size_t)E_ * OUT_ * H_ * 2);    // 4 MB
    bf16* h = (bf16*)alloc((size_t)MAXSLOTS * H_ * 2);       // 27 MB
    int* row_ids = (int*)alloc((size_t)MAXSLOTS * 4);
    int* rowslot = (int*)alloc((size_t)B_ * KTOP * 4);
    int* top_idx = (int*)alloc((size_t)B_ * KTOP * 4);
    float* top_gate = (float*)alloc((size_t)B_ * KTOP * 4);
    int* counts = (int*)alloc(E_ * 4);
    int* partial = (int*)alloc((size_t)GBLK * E_ * 4);       // 128 KB gating hists
    float* partial_imp = (float*)alloc(HBLK * E_ * 4);
    int* tile_expert = (int*)alloc(NTILES * 4);
    bf16* zero_row = (bf16*)alloc(IN_ * 2);
    float* wgT = (float*)alloc((size_t)E_ * IN_ * 4);        // 64 KB
    // eout (13.5 MB bf16) aliases xbf (16 MB): xbf dead after gemm1.
    bf16* eout = (bf16*)xbf;

    k_setup<<<dim3(2729), dim3(256), 0, stream>>>(
        W1, w1t, W2, w2t, row_ids, wgate, wgT, zero_row, tile_expert);
    k_gating<<<dim3(GBLK), dim3(256), 0, stream>>>(x, wgT, xbf, top_idx, top_gate, partial);
    k_scatterscan<<<dim3(HBLK), dim3(256), 0, stream>>>(
        top_idx, top_gate, partial, counts, tile_expert, row_ids, rowslot, partial_imp);
    k_gemm1<<<dim3(H_ / 128, NTILES), dim3(256), 0, stream>>>(
        xbf, w1t, b1, row_ids, tile_expert, zero_row, h);
    k_gemm2<<<dim3(NTILES), dim3(256), 0, stream>>>(
        h, w2t, b2, tile_expert, eout);
    k_combine<<<dim3(B_ / 4 + 1), dim3(256), 0, stream>>>(
        eout, rowslot, top_gate, y, partial_imp, counts, y + (size_t)B_ * OUT_);
}